// Round 5
// baseline (147.728 us; speedup 1.0000x reference)
//
#include <hip/hip_runtime.h>
#include <stdint.h>
#include <math.h>

// Problem geometry (fixed by the reference)
#define TT        256                       // T_STEPS
#define COLS      (16*8*1024*2)             // N*C*Do*Di = 262144
#define CS4       (COLS/4)                  // 65536
#define DMASK     (1024*2 - 1)              // Do*Di-1 (delay broadcast over N,C)
#define W         256                       // columns per block (1KB f32 per row)

__device__ __forceinline__ uint32_t rotl32(uint32_t x, int n) {
    return (x << n) | (x >> (32 - n));
}

// JAX threefry2x32-20, jax_threefry_partitionable=True (modern default):
// per-element counter (0, j), output = x0 ^ x1. Key = PRNGKey(42) = (0,42).
// Verified passing in rounds 2-4 — DO NOT TOUCH.
__device__ __forceinline__ uint32_t jax_bits_partitionable(uint32_t j) {
    uint32_t x0 = 0u, x1 = j;
    const uint32_t ks0 = 0u;
    const uint32_t ks1 = 42u;
    const uint32_t ks2 = 0x1BD11BDAu ^ 0u ^ 42u;
    x0 += ks0; x1 += ks1;
#define RND(r) { x0 += x1; x1 = rotl32(x1, r); x1 ^= x0; }
    RND(13) RND(15) RND(26) RND(6)
    x0 += ks1; x1 += ks2 + 1u;
    RND(17) RND(29) RND(16) RND(24)
    x0 += ks2; x1 += ks0 + 2u;
    RND(13) RND(15) RND(26) RND(6)
    x0 += ks0; x1 += ks1 + 3u;
    RND(17) RND(29) RND(16) RND(24)
    x0 += ks1; x1 += ks2 + 4u;
    RND(13) RND(15) RND(26) RND(6)
    x0 += ks2; x1 += ks0 + 5u;
#undef RND
    return x0 ^ x1;
}

__device__ __forceinline__ float sigmoidf_(float x) {
    return 1.0f / (1.0f + expf(-x));   // same formula as the passing rounds
}

__device__ __forceinline__ uint32_t bf16rne(float x) {
    uint32_t u = __float_as_uint(x);               // sigma: finite, non-NaN
    return (u + 0x7FFFu + ((u >> 16) & 1u)) >> 16; // round-to-nearest-even
}

// Fused kernel, 1024 threads, one block per 256 columns (1 block/CU, 149 KiB LDS):
//  phase 1 : each wave loads 1 KiB contiguous per t-row (float4), sigma once,
//            argmax folded in registers (fp32 -> indices bit-identical),
//            bf16(RNE) sigma tile -> LDS
//  phase 1b: 16-candidate/column reduce with (v>bm)||(v==bm&&i<bi) tie-break
//            (exact first-max), threefry bernoulli round + spike clamp -> d[c]
//  phase 2 : out[r,c] = tile[(r-d_c)&255][c]; each wave stores 1 KiB
//            contiguous per row (float4 of 4 rotated columns)
extern "C" __global__ __launch_bounds__(1024, 1)
void td_fused(const float* __restrict__ in, const float* __restrict__ delay,
              float* __restrict__ out) {
    __shared__ unsigned short tile16[TT * W];      // 128 KiB bf16 sigma tile
    __shared__ float          redv[16 * W];        // 16 KiB per-rowset max
    __shared__ unsigned char  redi[16 * W];        // 4 KiB per-rowset argmax
    __shared__ int            dint[W];             // 1 KiB

    const int c0  = blockIdx.x * W;
    const int tid = threadIdx.x;
    const int f   = tid & 63;                      // lane = float4 slot (4 cols)
    const int r0  = tid >> 6;                      // wave = row-set 0..15

    // ---- phase 1: 1KB/wave coalesced load + sigmoid + register argmax ----
    const float4* in4 = (const float4*)in;
    float bm0 = -1.0f, bm1 = -1.0f, bm2 = -1.0f, bm3 = -1.0f;
    int   bi0 = 0, bi1 = 0, bi2 = 0, bi3 = 0;
#pragma unroll 8
    for (int k = 0; k < 16; ++k) {
        const int t = r0 + (k << 4);               // increasing t per thread
        float4 v = in4[(size_t)t * CS4 + (c0 >> 2) + f];
        float s0 = sigmoidf_(v.x);
        float s1 = sigmoidf_(v.y);
        float s2 = sigmoidf_(v.z);
        float s3 = sigmoidf_(v.w);
        if (s0 > bm0) { bm0 = s0; bi0 = t; }       // strict > keeps first t
        if (s1 > bm1) { bm1 = s1; bi1 = t; }
        if (s2 > bm2) { bm2 = s2; bi2 = t; }
        if (s3 > bm3) { bm3 = s3; bi3 = t; }
        uint2 p;
        p.x = bf16rne(s0) | (bf16rne(s1) << 16);
        p.y = bf16rne(s2) | (bf16rne(s3) << 16);
        *(uint2*)&tile16[t * W + (f << 2)] = p;    // uniform banks, no conflict
    }
    *(float4*)&redv[r0 * W + (f << 2)] = make_float4(bm0, bm1, bm2, bm3);
    *(uint32_t*)&redi[r0 * W + (f << 2)] =
        (uint32_t)bi0 | ((uint32_t)bi1 << 8) |
        ((uint32_t)bi2 << 16) | ((uint32_t)bi3 << 24);
    __syncthreads();

    // ---- phase 1b: cross-rowset reduce + threefry round + clamp ----
    if (tid < W) {
        float bm = redv[tid];
        int   bi = redi[tid];
#pragma unroll
        for (int r = 1; r < 16; ++r) {
            float v = redv[r * W + tid];
            int   i = redi[r * W + tid];
            if (v > bm || (v == bm && i < bi)) { bm = v; bi = i; }  // first-max
        }
        const int jj = c0 + tid;
        float dl = delay[jj & DMASK];              // broadcast over (N,C)
        float df = floorf(dl);
        float fr = dl - df;                        // exact in fp32
        uint32_t bits = jax_bits_partitionable((uint32_t)jj);
        float u = __uint_as_float((bits >> 9) | 0x3f800000u) - 1.0f;  // [0,1)
        float dr = (u < fr) ? df + 1.0f : df;      // bernoulli round
        dr = fminf(dr, (float)(TT - 1 - bi));      // spike-no-wrap clamp
        dint[tid] = (int)dr;
    }
    __syncthreads();

    // ---- phase 2: rotate + 1KB/wave coalesced float4 stores ----
    const int4 dv = ((const int4*)dint)[f];        // d for cols 4f..4f+3
    int s0 = (r0 - dv.x) & (TT - 1);
    int s1 = (r0 - dv.y) & (TT - 1);
    int s2 = (r0 - dv.z) & (TT - 1);
    int s3 = (r0 - dv.w) & (TT - 1);
    const int    fc    = f << 2;
    const size_t obase = (size_t)c0 + fc;
#pragma unroll 8
    for (int k = 0; k < 16; ++k) {
        const int r = r0 + (k << 4);
        uint32_t h0 = tile16[s0 * W + fc + 0];
        uint32_t h1 = tile16[s1 * W + fc + 1];
        uint32_t h2 = tile16[s2 * W + fc + 2];
        uint32_t h3 = tile16[s3 * W + fc + 3];
        float4 o;
        o.x = __uint_as_float(h0 << 16);
        o.y = __uint_as_float(h1 << 16);
        o.z = __uint_as_float(h2 << 16);
        o.w = __uint_as_float(h3 << 16);
        *(float4*)&out[(size_t)r * COLS + obase] = o;
        s0 = (s0 + 16) & (TT - 1);
        s1 = (s1 + 16) & (TT - 1);
        s2 = (s2 + 16) & (TT - 1);
        s3 = (s3 + 16) & (TT - 1);
    }
}

extern "C" void kernel_launch(void* const* d_in, const int* in_sizes, int n_in,
                              void* d_out, int out_size, void* d_ws, size_t ws_size,
                              hipStream_t stream) {
    const float* in    = (const float*)d_in[0];   // (T,N,C,Do,Di) f32
    const float* delay = (const float*)d_in[1];   // (Do,Di) f32
    float* out = (float*)d_out;

    hipLaunchKernelGGL(td_fused, dim3(COLS / W), dim3(1024), 0, stream,
                       in, delay, out);
}

// Round 6
// 116.453 us; speedup vs baseline: 1.2686x; 1.2686x over previous
//
#include <hip/hip_runtime.h>
#include <stdint.h>
#include <math.h>

// Problem geometry (fixed by the reference)
#define TT        256                       // T_STEPS
#define COLS      (16*8*1024*2)             // N*C*Do*Di = 262144
#define CS4       (COLS/4)                  // 65536
#define DMASK     (1024*2 - 1)              // Do*Di-1 (delay broadcast over N,C)
#define W         64                        // columns per block (R3 structure)

__device__ __forceinline__ uint32_t rotl32(uint32_t x, int n) {
    return (x << n) | (x >> (32 - n));
}

// JAX threefry2x32-20, jax_threefry_partitionable=True (modern default):
// per-element counter (0, j), output = x0 ^ x1. Key = PRNGKey(42) = (0,42).
// Verified passing in rounds 2-5 — DO NOT TOUCH.
__device__ __forceinline__ uint32_t jax_bits_partitionable(uint32_t j) {
    uint32_t x0 = 0u, x1 = j;
    const uint32_t ks0 = 0u;
    const uint32_t ks1 = 42u;
    const uint32_t ks2 = 0x1BD11BDAu ^ 0u ^ 42u;
    x0 += ks0; x1 += ks1;
#define RND(r) { x0 += x1; x1 = rotl32(x1, r); x1 ^= x0; }
    RND(13) RND(15) RND(26) RND(6)
    x0 += ks1; x1 += ks2 + 1u;
    RND(17) RND(29) RND(16) RND(24)
    x0 += ks2; x1 += ks0 + 2u;
    RND(13) RND(15) RND(26) RND(6)
    x0 += ks0; x1 += ks1 + 3u;
    RND(17) RND(29) RND(16) RND(24)
    x0 += ks1; x1 += ks2 + 4u;
    RND(13) RND(15) RND(26) RND(6)
    x0 += ks2; x1 += ks0 + 5u;
#undef RND
    return x0 ^ x1;
}

// Cheap sigmoid: v_exp_f32 + v_rcp_f32 (~1 ulp). Used for output VALUES only;
// argmax ordering uses raw x (sigma strictly monotonic -> same index).
__device__ __forceinline__ float sigmoid_fast(float x) {
    return __builtin_amdgcn_rcpf(1.0f + __expf(-x));
}

// Fused kernel, one block per 64 columns (fp32 tile, 2 blocks/CU):
//  phase 1 : coalesced float4 copy of raw x -> LDS, argmax folded in registers
//            on RAW x (exact compares, no transcendentals)
//  phase 1b: 16-rowset reduce with (v>bm)||(v==bm&&i<bi) first-max tie-break,
//            threefry bernoulli round + spike clamp -> d[c]
//  phase 2 : out[r,c] = sigmoid_fast(tile[(r-d_c)&255][c]) ; bank = c%32 ->
//            conflict-free LDS reads, 256B/wave coalesced scalar stores
extern "C" __global__ __launch_bounds__(256, 2)
void td_fused(const float* __restrict__ in, const float* __restrict__ delay,
              float* __restrict__ out) {
    __shared__ float          tile[TT * W];        // 64 KiB raw-x tile
    __shared__ float          redv[16 * W];        // 4 KiB per-rowset max
    __shared__ unsigned char  redi[16 * W];        // 1 KiB per-rowset argmax
    __shared__ int            dint[W];

    const int c0  = blockIdx.x * W;
    const int tid = threadIdx.x;
    const int f   = tid & 15;                      // float4 slot (4 cols)
    const int r0  = tid >> 4;                      // row-set 0..15

    // ---- phase 1: pure copy + register argmax on raw x ----
    const float4* in4 = (const float4*)in;
    float bm0 = -1e30f, bm1 = -1e30f, bm2 = -1e30f, bm3 = -1e30f;
    int   bi0 = 0, bi1 = 0, bi2 = 0, bi3 = 0;
#pragma unroll 8
    for (int k = 0; k < 16; ++k) {
        const int t = r0 + (k << 4);               // increasing t per thread
        float4 v = in4[(size_t)t * CS4 + (c0 >> 2) + f];
        if (v.x > bm0) { bm0 = v.x; bi0 = t; }     // strict > keeps first t
        if (v.y > bm1) { bm1 = v.y; bi1 = t; }
        if (v.z > bm2) { bm2 = v.z; bi2 = t; }
        if (v.w > bm3) { bm3 = v.w; bi3 = t; }
        *(float4*)&tile[t * W + (f << 2)] = v;
    }
    *(float4*)&redv[r0 * W + (f << 2)] = make_float4(bm0, bm1, bm2, bm3);
    *(uint32_t*)&redi[r0 * W + (f << 2)] =
        (uint32_t)bi0 | ((uint32_t)bi1 << 8) |
        ((uint32_t)bi2 << 16) | ((uint32_t)bi3 << 24);
    __syncthreads();

    // ---- phase 1b: cross-rowset reduce + threefry round + clamp ----
    if (tid < W) {
        float bm = redv[tid];
        int   bi = redi[tid];
#pragma unroll
        for (int r = 1; r < 16; ++r) {
            float v = redv[r * W + tid];
            int   i = redi[r * W + tid];
            if (v > bm || (v == bm && i < bi)) { bm = v; bi = i; }  // first-max
        }
        const int jj = c0 + tid;
        float dl = delay[jj & DMASK];              // broadcast over (N,C)
        float df = floorf(dl);
        float fr = dl - df;                        // exact in fp32
        uint32_t bits = jax_bits_partitionable((uint32_t)jj);
        float u = __uint_as_float((bits >> 9) | 0x3f800000u) - 1.0f;  // [0,1)
        float dr = (u < fr) ? df + 1.0f : df;      // bernoulli round
        dr = fminf(dr, (float)(TT - 1 - bi));      // spike-no-wrap clamp
        dint[tid] = (int)dr;
    }
    __syncthreads();

    // ---- phase 2: rotate + cheap sigmoid + coalesced scalar stores ----
    const int c = tid & 63;
    const int w = tid >> 6;                        // wave id 0..3
    const int d = dint[c];
    int s = (w - d) & (TT - 1);
    const size_t obase = (size_t)w * COLS + c0 + c;
#pragma unroll
    for (int k = 0; k < 64; ++k) {                 // row r = 4k + w
        out[obase + (size_t)(k * 4) * COLS] = sigmoid_fast(tile[s * W + c]);
        s = (s + 4) & (TT - 1);
    }
}

extern "C" void kernel_launch(void* const* d_in, const int* in_sizes, int n_in,
                              void* d_out, int out_size, void* d_ws, size_t ws_size,
                              hipStream_t stream) {
    const float* in    = (const float*)d_in[0];   // (T,N,C,Do,Di) f32
    const float* delay = (const float*)d_in[1];   // (Do,Di) f32
    float* out = (float*)d_out;

    hipLaunchKernelGGL(td_fused, dim3(COLS / W), dim3(256), 0, stream,
                       in, delay, out);
}

// Round 7
// 92.081 us; speedup vs baseline: 1.6043x; 1.2647x over previous
//
#include <hip/hip_runtime.h>
#include <stdint.h>
#include <math.h>

// Problem geometry (fixed by the reference)
#define TT        256                       // T_STEPS
#define COLS      (16*8*1024*2)             // N*C*Do*Di = 262144
#define CS4       (COLS/4)                  // 65536
#define DMASK     (1024*2 - 1)              // Do*Di-1 (delay broadcast over N,C)
#define W         64                        // columns per block (R3/R6 structure)

__device__ __forceinline__ uint32_t rotl32(uint32_t x, int n) {
    return (x << n) | (x >> (32 - n));
}

// JAX threefry2x32-20, jax_threefry_partitionable=True (modern default):
// per-element counter (0, j), output = x0 ^ x1. Key = PRNGKey(42) = (0,42).
// Verified passing in rounds 2-6 — DO NOT TOUCH.
__device__ __forceinline__ uint32_t jax_bits_partitionable(uint32_t j) {
    uint32_t x0 = 0u, x1 = j;
    const uint32_t ks0 = 0u;
    const uint32_t ks1 = 42u;
    const uint32_t ks2 = 0x1BD11BDAu ^ 0u ^ 42u;
    x0 += ks0; x1 += ks1;
#define RND(r) { x0 += x1; x1 = rotl32(x1, r); x1 ^= x0; }
    RND(13) RND(15) RND(26) RND(6)
    x0 += ks1; x1 += ks2 + 1u;
    RND(17) RND(29) RND(16) RND(24)
    x0 += ks2; x1 += ks0 + 2u;
    RND(13) RND(15) RND(26) RND(6)
    x0 += ks0; x1 += ks1 + 3u;
    RND(17) RND(29) RND(16) RND(24)
    x0 += ks1; x1 += ks2 + 4u;
    RND(13) RND(15) RND(26) RND(6)
    x0 += ks2; x1 += ks0 + 5u;
#undef RND
    return x0 ^ x1;
}

// Cheap sigmoid: v_exp_f32 + v_rcp_f32 (~1 ulp). Output VALUES only;
// argmax ordering uses raw x (sigma strictly monotonic -> same index).
__device__ __forceinline__ float sigmoid_fast(float x) {
    return __builtin_amdgcn_rcpf(1.0f + __expf(-x));
}

// Fused kernel, one block per 64 columns (fp32 tile, 2 blocks/CU):
//  phase 1 : coalesced float4 copy of raw x -> LDS, argmax folded in registers
//            on RAW x (exact compares, no transcendentals)
//  phase 1b: 16-rowset reduce with (v>bm)||(v==bm&&i<bi) first-max tie-break,
//            threefry bernoulli round + spike clamp -> d[c]
//  phase 2 : out[r,c] = sigmoid_fast(tile[(r-d_c)&255][c]); bank = c%32 ->
//            conflict-free LDS reads; NON-TEMPORAL 256B/wave stores so the
//            write-once output doesn't evict the L3-resident input (input
//            = 268 MB ~= the 256 MiB Infinity Cache; R5 showed FETCH=134MB,
//            i.e. half the input was surviving in L3 across replays).
extern "C" __global__ __launch_bounds__(256, 2)
void td_fused(const float* __restrict__ in, const float* __restrict__ delay,
              float* __restrict__ out) {
    __shared__ float          tile[TT * W];        // 64 KiB raw-x tile
    __shared__ float          redv[16 * W];        // 4 KiB per-rowset max
    __shared__ unsigned char  redi[16 * W];        // 1 KiB per-rowset argmax
    __shared__ int            dint[W];

    const int c0  = blockIdx.x * W;
    const int tid = threadIdx.x;
    const int f   = tid & 15;                      // float4 slot (4 cols)
    const int r0  = tid >> 4;                      // row-set 0..15

    // ---- phase 1: pure copy + register argmax on raw x ----
    const float4* in4 = (const float4*)in;
    float bm0 = -1e30f, bm1 = -1e30f, bm2 = -1e30f, bm3 = -1e30f;
    int   bi0 = 0, bi1 = 0, bi2 = 0, bi3 = 0;
#pragma unroll 8
    for (int k = 0; k < 16; ++k) {
        const int t = r0 + (k << 4);               // increasing t per thread
        float4 v = in4[(size_t)t * CS4 + (c0 >> 2) + f];
        if (v.x > bm0) { bm0 = v.x; bi0 = t; }     // strict > keeps first t
        if (v.y > bm1) { bm1 = v.y; bi1 = t; }
        if (v.z > bm2) { bm2 = v.z; bi2 = t; }
        if (v.w > bm3) { bm3 = v.w; bi3 = t; }
        *(float4*)&tile[t * W + (f << 2)] = v;
    }
    *(float4*)&redv[r0 * W + (f << 2)] = make_float4(bm0, bm1, bm2, bm3);
    *(uint32_t*)&redi[r0 * W + (f << 2)] =
        (uint32_t)bi0 | ((uint32_t)bi1 << 8) |
        ((uint32_t)bi2 << 16) | ((uint32_t)bi3 << 24);
    __syncthreads();

    // ---- phase 1b: cross-rowset reduce + threefry round + clamp ----
    if (tid < W) {
        float bm = redv[tid];
        int   bi = redi[tid];
#pragma unroll
        for (int r = 1; r < 16; ++r) {
            float v = redv[r * W + tid];
            int   i = redi[r * W + tid];
            if (v > bm || (v == bm && i < bi)) { bm = v; bi = i; }  // first-max
        }
        const int jj = c0 + tid;
        float dl = delay[jj & DMASK];              // broadcast over (N,C)
        float df = floorf(dl);
        float fr = dl - df;                        // exact in fp32
        uint32_t bits = jax_bits_partitionable((uint32_t)jj);
        float u = __uint_as_float((bits >> 9) | 0x3f800000u) - 1.0f;  // [0,1)
        float dr = (u < fr) ? df + 1.0f : df;      // bernoulli round
        dr = fminf(dr, (float)(TT - 1 - bi));      // spike-no-wrap clamp
        dint[tid] = (int)dr;
    }
    __syncthreads();

    // ---- phase 2: rotate + cheap sigmoid + non-temporal coalesced stores ----
    const int c = tid & 63;
    const int w = tid >> 6;                        // wave id 0..3
    const int d = dint[c];
    int s = (w - d) & (TT - 1);
    float* op = out + (size_t)w * COLS + c0 + c;
#pragma unroll
    for (int k = 0; k < 64; ++k) {                 // row r = 4k + w
        __builtin_nontemporal_store(sigmoid_fast(tile[s * W + c]),
                                    op + (size_t)(k * 4) * COLS);
        s = (s + 4) & (TT - 1);
    }
}

extern "C" void kernel_launch(void* const* d_in, const int* in_sizes, int n_in,
                              void* d_out, int out_size, void* d_ws, size_t ws_size,
                              hipStream_t stream) {
    const float* in    = (const float*)d_in[0];   // (T,N,C,Do,Di) f32
    const float* delay = (const float*)d_in[1];   // (Do,Di) f32
    float* out = (float*)d_out;

    hipLaunchKernelGGL(td_fused, dim3(COLS / W), dim3(256), 0, stream,
                       in, delay, out);
}

// Round 8
// 87.735 us; speedup vs baseline: 1.6838x; 1.0495x over previous
//
#include <hip/hip_runtime.h>
#include <stdint.h>
#include <math.h>

// Problem geometry (fixed by the reference)
#define TT        256                       // T_STEPS
#define COLS      (16*8*1024*2)             // N*C*Do*Di = 262144
#define CS4       (COLS/4)                  // 65536
#define DMASK     (1024*2 - 1)              // Do*Di-1 (delay broadcast over N,C)
#define W         32                        // columns per block (4 blocks/CU)

__device__ __forceinline__ uint32_t rotl32(uint32_t x, int n) {
    return (x << n) | (x >> (32 - n));
}

// JAX threefry2x32-20, jax_threefry_partitionable=True (modern default):
// per-element counter (0, j), output = x0 ^ x1. Key = PRNGKey(42) = (0,42).
// Verified passing in rounds 2-7 — DO NOT TOUCH.
__device__ __forceinline__ uint32_t jax_bits_partitionable(uint32_t j) {
    uint32_t x0 = 0u, x1 = j;
    const uint32_t ks0 = 0u;
    const uint32_t ks1 = 42u;
    const uint32_t ks2 = 0x1BD11BDAu ^ 0u ^ 42u;
    x0 += ks0; x1 += ks1;
#define RND(r) { x0 += x1; x1 = rotl32(x1, r); x1 ^= x0; }
    RND(13) RND(15) RND(26) RND(6)
    x0 += ks1; x1 += ks2 + 1u;
    RND(17) RND(29) RND(16) RND(24)
    x0 += ks2; x1 += ks0 + 2u;
    RND(13) RND(15) RND(26) RND(6)
    x0 += ks0; x1 += ks1 + 3u;
    RND(17) RND(29) RND(16) RND(24)
    x0 += ks1; x1 += ks2 + 4u;
    RND(13) RND(15) RND(26) RND(6)
    x0 += ks2; x1 += ks0 + 5u;
#undef RND
    return x0 ^ x1;
}

// Cheap sigmoid: v_exp_f32 + v_rcp_f32 (~1 ulp). Output VALUES only;
// argmax ordering uses raw x (sigma strictly monotonic -> same index).
__device__ __forceinline__ float sigmoid_fast(float x) {
    return __builtin_amdgcn_rcpf(1.0f + __expf(-x));
}

// Fused kernel, one block per 32 columns (37.1 KiB LDS -> 4 blocks/CU,
// 16 waves/CU: doubles inter-block phase overlap vs round 7's 2 blocks/CU;
// the block is inherently serial: argmax over all T must precede stores):
//  phase 1 : coalesced float4 copy of raw x -> LDS, argmax folded in registers
//  phase 1b: 32-rowset first-max reduce, threefry round + spike clamp -> d[c]
//  phase 2 : out[r,c] = sigmoid_fast(tile[(r-d_c)&255][c]); 2 lanes/bank LDS
//            reads (free); NON-TEMPORAL stores (write-once output must not
//            evict the L3-resident input — R7's 21% win, kept).
extern "C" __global__ __launch_bounds__(256, 4)
void td_fused(const float* __restrict__ in, const float* __restrict__ delay,
              float* __restrict__ out) {
    __shared__ float          tile[TT * W];        // 32 KiB raw-x tile
    __shared__ float          redv[32 * W];        // 4 KiB per-rowset max
    __shared__ unsigned char  redi[32 * W];        // 1 KiB per-rowset argmax
    __shared__ int            dint[W];

    const int c0  = blockIdx.x * W;
    const int tid = threadIdx.x;
    const int f   = tid & 7;                       // float4 slot (4 cols)
    const int r0  = tid >> 3;                      // row-set 0..31

    // ---- phase 1: pure copy + register argmax on raw x ----
    const float4* in4 = (const float4*)in;
    float bm0 = -1e30f, bm1 = -1e30f, bm2 = -1e30f, bm3 = -1e30f;
    int   bi0 = 0, bi1 = 0, bi2 = 0, bi3 = 0;
#pragma unroll
    for (int k = 0; k < 8; ++k) {
        const int t = r0 + (k << 5);               // increasing t per thread
        float4 v = in4[(size_t)t * CS4 + (c0 >> 2) + f];
        if (v.x > bm0) { bm0 = v.x; bi0 = t; }     // strict > keeps first t
        if (v.y > bm1) { bm1 = v.y; bi1 = t; }
        if (v.z > bm2) { bm2 = v.z; bi2 = t; }
        if (v.w > bm3) { bm3 = v.w; bi3 = t; }
        *(float4*)&tile[t * W + (f << 2)] = v;
    }
    *(float4*)&redv[r0 * W + (f << 2)] = make_float4(bm0, bm1, bm2, bm3);
    *(uint32_t*)&redi[r0 * W + (f << 2)] =
        (uint32_t)bi0 | ((uint32_t)bi1 << 8) |
        ((uint32_t)bi2 << 16) | ((uint32_t)bi3 << 24);
    __syncthreads();

    // ---- phase 1b: cross-rowset reduce + threefry round + clamp ----
    if (tid < W) {
        float bm = redv[tid];
        int   bi = redi[tid];
#pragma unroll
        for (int r = 1; r < 32; ++r) {
            float v = redv[r * W + tid];
            int   i = redi[r * W + tid];
            if (v > bm || (v == bm && i < bi)) { bm = v; bi = i; }  // first-max
        }
        const int jj = c0 + tid;
        float dl = delay[jj & DMASK];              // broadcast over (N,C)
        float df = floorf(dl);
        float fr = dl - df;                        // exact in fp32
        uint32_t bits = jax_bits_partitionable((uint32_t)jj);
        float u = __uint_as_float((bits >> 9) | 0x3f800000u) - 1.0f;  // [0,1)
        float dr = (u < fr) ? df + 1.0f : df;      // bernoulli round
        dr = fminf(dr, (float)(TT - 1 - bi));      // spike-no-wrap clamp
        dint[tid] = (int)dr;
    }
    __syncthreads();

    // ---- phase 2: rotate + cheap sigmoid + non-temporal coalesced stores ----
    const int c = tid & 31;
    const int w = tid >> 5;                        // row-group 0..7
    const int d = dint[c];
    int s = (w - d) & (TT - 1);
    float* op = out + (size_t)w * COLS + c0 + c;
#pragma unroll
    for (int k = 0; k < 32; ++k) {                 // row r = 8k + w
        __builtin_nontemporal_store(sigmoid_fast(tile[s * W + c]),
                                    op + (size_t)(k * 8) * COLS);
        s = (s + 8) & (TT - 1);
    }
}

extern "C" void kernel_launch(void* const* d_in, const int* in_sizes, int n_in,
                              void* d_out, int out_size, void* d_ws, size_t ws_size,
                              hipStream_t stream) {
    const float* in    = (const float*)d_in[0];   // (T,N,C,Do,Di) f32
    const float* delay = (const float*)d_in[1];   // (Do,Di) f32
    float* out = (float*)d_out;

    hipLaunchKernelGGL(td_fused, dim3(COLS / W), dim3(256), 0, stream,
                       in, delay, out);
}